// Round 7
// baseline (143.746 us; speedup 1.0000x reference)
//
#include <hip/hip_runtime.h>
#include <math.h>

#define B_SZ 2
#define N_PRED 256
#define M_GT 32
#define L_TOK 16
#define V_VOCAB 32000
#define P_POS 15            // L_TOK-1 predicted positions
#define NROW 960            // B*M*P = 2*32*15 caption rows
#define HALF4 4000          // float4s per half-row (32000/4/2)
#define CPAD 36             // cost row stride (floats): 144B, 16B-aligned

__device__ __forceinline__ float giou_f(float4 b1, float4 b2) {
    float ax1 = fminf(b1.x, b1.z), ay1 = fminf(b1.y, b1.w);
    float ax2 = fmaxf(b1.x, b1.z), ay2 = fmaxf(b1.y, b1.w);
    float bx1 = fminf(b2.x, b2.z), by1 = fminf(b2.y, b2.w);
    float bx2 = fmaxf(b2.x, b2.z), by2 = fmaxf(b2.y, b2.w);
    float xi1 = fmaxf(ax1, bx1), yi1 = fmaxf(ay1, by1);
    float xi2 = fminf(ax2, bx2), yi2 = fminf(ay2, by2);
    float inter = fmaxf(xi2 - xi1, 0.f) * fmaxf(yi2 - yi1, 0.f);
    float a1 = (ax2 - ax1) * (ay2 - ay1);
    float a2 = (bx2 - bx1) * (by2 - by1);
    float uni = a1 + a2 - inter;
    float iou = inter / (uni + 1e-7f);
    float xe1 = fminf(ax1, bx1), ye1 = fminf(ay1, by1);
    float xe2 = fmaxf(ax2, bx2), ye2 = fmaxf(ay2, by2);
    float enc = (xe2 - xe1) * (ye2 - ye1);
    return iou - (enc - uni) / (enc + 1e-7f);
}

// One DPP min-scan step on the (khi,klo) u64 key (verified correct in R5).
// Lanes with no source get old=0xFFFFFFFF -> key ~0ULL -> no-op in min.
#define DPP_STEP(ctrl, rmask)                                              \
    {                                                                      \
        unsigned nlo = (unsigned)__builtin_amdgcn_update_dpp(              \
            (int)0xFFFFFFFF, (int)klo, (ctrl), (rmask), 0xF, false);       \
        unsigned nhi = (unsigned)__builtin_amdgcn_update_dpp(              \
            (int)0xFFFFFFFF, (int)khi, (ctrl), (rmask), 0xF, false);       \
        if (nhi < khi || (nhi == khi && nlo < klo)) { khi = nhi; klo = nlo; } \
    }

// One block of 256 threads per sample.
// Phase 1 (4 waves): thread tid computes cost row tid -> LDS costS (rows
//   16B-aligned for b128 rescan reads), per-row best -> LDS, BCE partial.
// Phase 2 (wave 0 only): 4 rows/lane; cached bests in REGISTERS (8 regs,
//   no spill); rescan reads LDS row via 8 x float4; global argmin via u64
//   key (cost_bits<<13 | flat; costs>0 so float-bit order == value order;
//   min == lexicographic (value,flat) == jnp.argmin first-occurrence)
//   reduced by 6-step DPP min-scan -> lane 63 -> readlane. No barriers or
//   cross-wave LDS traffic inside the 32-iteration greedy loop.
__global__ __launch_bounds__(256, 1) void match_bbox_obj_kernel(
    const float* __restrict__ pred_boxes, const float* __restrict__ pred_obj,
    const float* __restrict__ gt_boxes,
    int* __restrict__ pis, int* __restrict__ gjs,
    float* __restrict__ bbox_out, float* __restrict__ obj_out)
{
    const int b   = blockIdx.x;
    const int tid = threadIdx.x;          // = pred row index in phase 1
    const int wv  = tid >> 6;
    const int ln  = tid & 63;

    __shared__ float  costS[N_PRED][CPAD];
    __shared__ float  rbv[N_PRED];
    __shared__ int    rbj[N_PRED];
    __shared__ float  poS[N_PRED];
    __shared__ float4 pbS[N_PRED];
    __shared__ float4 gbS[M_GT];
    __shared__ float  obase[4];

    if (tid < M_GT) gbS[tid] = ((const float4*)gt_boxes)[b * M_GT + tid];
    const float4 p  = ((const float4*)pred_boxes)[b * N_PRED + tid];
    const float  po = pred_obj[b * N_PRED + tid];
    pbS[tid] = p;
    poS[tid] = po;
    __syncthreads();

    // ---- phase 1: cost row + per-row best + BCE partial ----
    const float objc = 1.f - 1.f / (1.f + __expf(-po));
    {
        float bv = INFINITY; int bj = 0;
#pragma unroll
        for (int j = 0; j < M_GT; ++j) {
            float4 g = gbS[j];
            float l1 = fabsf(p.x - g.x) + fabsf(p.y - g.y) +
                       fabsf(p.z - g.z) + fabsf(p.w - g.w);
            float c = l1 + (1.f - giou_f(p, g)) + objc;
            costS[tid][j] = c;
            if (c < bv) { bv = c; bj = j; }   // strict < -> smallest j on tie
        }
        rbv[tid] = bv; rbj[tid] = bj;
    }
    {
        float ob = fmaxf(po, 0.f) + log1pf(__expf(-fabsf(po)));
        for (int off = 32; off > 0; off >>= 1) ob += __shfl_xor(ob, off);
        if (ln == 0) obase[wv] = ob;
    }
    __syncthreads();

    if (wv != 0) return;   // wave 0 runs the serial greedy alone

    // ---- phase 2: greedy matching, wave 0 ----
    float bestv[4];
    int   bestj[4];
#pragma unroll
    for (int q = 0; q < 4; ++q) {
        const int i = ln + 64 * q;
        bestv[q] = rbv[i]; bestj[q] = rbj[i];
    }

    unsigned colUsed = 0;
    int rowUsed = 0;            // bitmask over q
    int my_pi = 0, my_gj = 0;   // lane t holds match t (t < 32)

    for (int t = 0; t < M_GT; ++t) {
        unsigned klo = 0xFFFFFFFFu, khi = 0xFFFFFFFFu;
#pragma unroll
        for (int q = 0; q < 4; ++q) {
            if (!((rowUsed >> q) & 1)) {
                unsigned cb = __float_as_uint(bestv[q]);
                unsigned h = cb >> 19;
                unsigned l = (cb << 13) | (unsigned)((ln + 64 * q) * M_GT + bestj[q]);
                if (h < khi || (h == khi && l < klo)) { khi = h; klo = l; }
            }
        }
        DPP_STEP(0x111, 0xF);   // row_shr:1
        DPP_STEP(0x112, 0xF);   // row_shr:2
        DPP_STEP(0x114, 0xF);   // row_shr:4
        DPP_STEP(0x118, 0xF);   // row_shr:8
        DPP_STEP(0x142, 0xA);   // row_bcast15 -> rows 1,3
        DPP_STEP(0x143, 0xC);   // row_bcast31 -> rows 2,3
        const unsigned glo = (unsigned)__builtin_amdgcn_readlane((int)klo, 63);

        const int flat = (int)(glo & 0x1FFFu);
        const int wi = flat >> 5;
        const int wj = flat & 31;
        if (ln == t) { my_pi = wi; my_gj = wj; }
        colUsed |= 1u << wj;
        if ((wi & 63) == ln) rowUsed |= 1 << (wi >> 6);
        // rescan rows whose cached best column was just consumed (LDS b128)
#pragma unroll
        for (int q = 0; q < 4; ++q) {
            if (!((rowUsed >> q) & 1) && bestj[q] == wj) {
                const float4* rp = (const float4*)&costS[ln + 64 * q][0];
                float bv = INFINITY; int bj = 0;
#pragma unroll
                for (int j4 = 0; j4 < 8; ++j4) {
                    float4 c4 = rp[j4];
#pragma unroll
                    for (int e = 0; e < 4; ++e) {
                        int j = j4 * 4 + e;
                        float c = ((colUsed >> j) & 1) ? INFINITY
                                 : (e == 0 ? c4.x : e == 1 ? c4.y : e == 2 ? c4.z : c4.w);
                        if (c < bv) { bv = c; bj = j; }
                    }
                }
                bestv[q] = bv; bestj[q] = bj;
            }
        }
    }

    if (ln < M_GT) {
        pis[b * M_GT + ln] = my_pi;
        gjs[b * M_GT + ln] = my_gj;
    }

    // bbox loss over matched pairs + matched-po sum (lanes 0..31)
    float l1sum = 0.f, gsum = 0.f, mpo = 0.f;
    if (ln < M_GT) {
        float4 mp = pbS[my_pi];
        float4 mg = gbS[my_gj];
        l1sum = fabsf(mp.x - mg.x) + fabsf(mp.y - mg.y) +
                fabsf(mp.z - mg.z) + fabsf(mp.w - mg.w);
        gsum = 1.f - giou_f(mp, mg);
        mpo  = poS[my_pi];
    }
    for (int off = 32; off > 0; off >>= 1) {
        l1sum += __shfl_xor(l1sum, off);
        gsum  += __shfl_xor(gsum,  off);
        mpo   += __shfl_xor(mpo,   off);
    }
    if (ln == 0) {
        float l1_loss   = l1sum / 128.f;                       // mean over (32,4)
        float giou_loss = fminf(fmaxf(gsum / 32.f, 0.f), 2.f); // clip [0,2]
        bbox_out[b] = fmaxf(l1_loss + giou_loss, 0.f);
        float ot = obase[0] + obase[1] + obase[2] + obase[3] - mpo;
        obj_out[b]  = fmaxf(ot / 256.f, 0.f);
    }
}

// ===== caption (byte-identical to R6) =====
__global__ __launch_bounds__(256) void caption_lse_kernel(
    const float* __restrict__ cl, const int* __restrict__ gt_tokens,
    const int* __restrict__ pis, const int* __restrict__ gjs,
    float* __restrict__ pm, float* __restrict__ ps, float* __restrict__ tl)
{
    const int bid = blockIdx.x;
    const int h   = bid & 1;
    const int r   = bid >> 1;
    const int b   = r / (M_GT * P_POS);
    const int rem = r % (M_GT * P_POS);
    const int k   = rem / P_POS;
    const int p   = rem % P_POS;
    const int tid = threadIdx.x;
    const int wv  = tid >> 6;
    const int ln  = tid & 63;

    const int n = pis[b * M_GT + k];
    const float* row = cl + ((size_t)(b * N_PRED + n) * L_TOK + p) * V_VOCAB;
    const float4* row4 = (const float4*)row;

    const int base = h * HALF4;
    const int end  = base + HALF4;
    float m0 = -INFINITY, s0 = 0.f;
    float m1 = -INFINITY, s1 = 0.f;
    for (int idx = base + tid; idx < end; idx += 512) {
        {
            float4 v = row4[idx];
            float m4 = fmaxf(fmaxf(v.x, v.y), fmaxf(v.z, v.w));
            float mn = fmaxf(m0, m4);
            s0 = s0 * __expf(m0 - mn) +
                 __expf(v.x - mn) + __expf(v.y - mn) +
                 __expf(v.z - mn) + __expf(v.w - mn);
            m0 = mn;
        }
        int i2 = idx + 256;
        if (i2 < end) {
            float4 v = row4[i2];
            float m4 = fmaxf(fmaxf(v.x, v.y), fmaxf(v.z, v.w));
            float mn = fmaxf(m1, m4);
            s1 = s1 * __expf(m1 - mn) +
                 __expf(v.x - mn) + __expf(v.y - mn) +
                 __expf(v.z - mn) + __expf(v.w - mn);
            m1 = mn;
        }
    }
    float m = fmaxf(m0, m1);
    float s = s0 * __expf(m0 - m) + s1 * __expf(m1 - m);

    for (int off = 32; off > 0; off >>= 1) {
        float mo = __shfl_xor(m, off);
        float so = __shfl_xor(s, off);
        float mm = fmaxf(m, mo);
        s = s * __expf(m - mm) + so * __expf(mo - mm);
        m = mm;
    }

    __shared__ float wm[4], wsum[4];
    if (ln == 0) { wm[wv] = m; wsum[wv] = s; }
    __syncthreads();
    if (tid == 0) {
        float mm = fmaxf(fmaxf(wm[0], wm[1]), fmaxf(wm[2], wm[3]));
        float st = wsum[0] * __expf(wm[0] - mm) + wsum[1] * __expf(wm[1] - mm) +
                   wsum[2] * __expf(wm[2] - mm) + wsum[3] * __expf(wm[3] - mm);
        pm[bid] = mm;
        ps[bid] = st;
        if (h == 0) {
            const int gj  = gjs[b * M_GT + k];
            const int tgt = gt_tokens[(b * M_GT + gj) * L_TOK + (p + 1)];
            tl[r] = row[tgt];
        }
    }
}

// ===== finalize (byte-identical to R6) =====
__global__ __launch_bounds__(64) void finalize_kernel(
    const float* __restrict__ pm, const float* __restrict__ ps,
    const float* __restrict__ tl,
    const float* __restrict__ bbox, const float* __restrict__ obj,
    float* __restrict__ out)
{
    const int l = threadIdx.x;      // l = b*32 + k
    float sum = 0.f;
#pragma unroll
    for (int p = 0; p < P_POS; ++p) {
        int r = l * P_POS + p;
        float m0 = pm[2*r],   s0 = ps[2*r];
        float m1 = pm[2*r+1], s1 = ps[2*r+1];
        float mm = fmaxf(m0, m1);
        float s  = s0 * __expf(m0 - mm) + s1 * __expf(m1 - mm);
        sum += mm + __logf(s) - tl[r];
    }
    float cek = fmaxf(sum / (float)P_POS, 0.f);   // clip(ce,0) per match
    for (int off = 16; off > 0; off >>= 1) cek += __shfl_xor(cek, off);
    float cap_b = fmaxf(cek / (float)M_GT, 0.f);  // clip(mean,0) per sample
    float cap0 = __shfl(cap_b, 0);
    float cap1 = __shfl(cap_b, 32);
    if (l == 0) {
        float bb0 = bbox[0], bb1 = bbox[1];
        float ob0 = obj[0],  ob1 = obj[1];
        float per0 = 5.f * bb0 + 0.1f * cap0 + ob0;
        float per1 = 5.f * bb1 + 0.1f * cap1 + ob1;
        out[0] = fmaxf(0.5f * (per0 + per1), 0.f);
        out[1] = 5.f  * 0.5f * (bb0 + bb1);
        out[2] = 0.1f * 0.5f * (cap0 + cap1);
        out[3] = 0.5f * (ob0 + ob1);
    }
}

extern "C" void kernel_launch(void* const* d_in, const int* in_sizes, int n_in,
                              void* d_out, int out_size, void* d_ws, size_t ws_size,
                              hipStream_t stream) {
    const float* pred_boxes = (const float*)d_in[0];   // (2,256,4)
    const float* pred_obj   = (const float*)d_in[1];   // (2,256)
    const float* cap_logits = (const float*)d_in[2];   // (2,256,16,32000)
    const float* gt_boxes   = (const float*)d_in[3];   // (2,32,4)
    const int*   gt_tokens  = (const int*)d_in[4];     // (2,32,16) int32
    float* out = (float*)d_out;                        // (4,)

    int*   pis  = (int*)d_ws;                  // 64 ints
    int*   gjs  = pis + B_SZ * M_GT;           // 64 ints
    float* bbox = (float*)(gjs + B_SZ * M_GT); // 2 floats
    float* obj  = bbox + B_SZ;                 // 2 floats
    float* pm   = obj + B_SZ;                  // 1920 floats (960 rows x 2)
    float* ps   = pm + 2 * NROW;               // 1920 floats
    float* tl   = ps + 2 * NROW;               // 960 floats

    match_bbox_obj_kernel<<<B_SZ, 256, 0, stream>>>(
        pred_boxes, pred_obj, gt_boxes, pis, gjs, bbox, obj);
    caption_lse_kernel<<<2 * NROW, 256, 0, stream>>>(
        cap_logits, gt_tokens, pis, gjs, pm, ps, tl);
    finalize_kernel<<<1, 64, 0, stream>>>(pm, ps, tl, bbox, obj, out);
}

// Round 8
// 77.551 us; speedup vs baseline: 1.8536x; 1.8536x over previous
//
#include <hip/hip_runtime.h>
#include <math.h>

#define B_SZ 2
#define N_PRED 256
#define M_GT 32
#define L_TOK 16
#define V_VOCAB 32000
#define P_POS 15            // L_TOK-1 predicted positions
#define NROW 960            // B*M*P = 2*32*15 caption rows
#define HALF4 4000          // float4s per half-row (32000/4/2)

__device__ __forceinline__ float giou_f(float4 b1, float4 b2) {
    float ax1 = fminf(b1.x, b1.z), ay1 = fminf(b1.y, b1.w);
    float ax2 = fmaxf(b1.x, b1.z), ay2 = fmaxf(b1.y, b1.w);
    float bx1 = fminf(b2.x, b2.z), by1 = fminf(b2.y, b2.w);
    float bx2 = fmaxf(b2.x, b2.z), by2 = fmaxf(b2.y, b2.w);
    float xi1 = fmaxf(ax1, bx1), yi1 = fmaxf(ay1, by1);
    float xi2 = fminf(ax2, bx2), yi2 = fminf(ay2, by2);
    float inter = fmaxf(xi2 - xi1, 0.f) * fmaxf(yi2 - yi1, 0.f);
    float a1 = (ax2 - ax1) * (ay2 - ay1);
    float a2 = (bx2 - bx1) * (by2 - by1);
    float uni = a1 + a2 - inter;
    float iou = inter / (uni + 1e-7f);
    float xe1 = fminf(ax1, bx1), ye1 = fminf(ay1, by1);
    float xe2 = fmaxf(ax2, bx2), ye2 = fmaxf(ay2, by2);
    float enc = (xe2 - xe1) * (ye2 - ye1);
    return iou - (enc - uni) / (enc + 1e-7f);
}

// 6-step DPP inclusive min-scan step on 32-bit unsigned `scan`; lanes with
// no source get old=0xFFFFFFFF (never wins). Verified on HW in R5/R7.
#define DPP_MIN(ctrl, rmask)                                               \
    {                                                                      \
        unsigned nv = (unsigned)__builtin_amdgcn_update_dpp(               \
            (int)0xFFFFFFFF, (int)scan, (ctrl), (rmask), 0xF, false);      \
        if (nv < scan) scan = nv;                                          \
    }

// 256 threads (4 waves) per sample; thread tid owns pred row tid; cost row
// cr[32] in REGISTERS (R4/R6-proven: rescan must be register-resident).
// Per greedy iteration:
//   1. per-thread candidate value (float bits; costs>0 so unsigned order ==
//      float order), sentinel 0xFFFFFFFF for used rows.
//   2. intra-wave DPP min-scan (pure VALU) -> lane63 -> readlane = vmin;
//      ballot(cand==vmin) -> lowest lane (= smallest row in wave) ->
//      readlane its flat = tid*32+bestj  -> exact first-occurrence.
//   3. cross-wave: lane0 writes (vmin<<32)|flat to wkeyd[t&1][wv]; ONE
//      barrier; all read 4 u64s, min = lexicographic (value, flat) ==
//      jnp.argmin first-occurrence over row-major i*M+j.
//   4. update masks; rescan own register row if its best column died.
__global__ __launch_bounds__(256) void match_bbox_obj_kernel(
    const float* __restrict__ pred_boxes, const float* __restrict__ pred_obj,
    const float* __restrict__ gt_boxes,
    int* __restrict__ pis, int* __restrict__ gjs,
    float* __restrict__ bbox_out, float* __restrict__ obj_out)
{
    const int b   = blockIdx.x;
    const int tid = threadIdx.x;          // = pred row index
    const int wv  = tid >> 6;
    const int ln  = tid & 63;

    __shared__ float4 gbS[M_GT];
    __shared__ float4 pbS[N_PRED];
    __shared__ unsigned long long wkeyd[2][4];
    __shared__ float wosum[4];

    if (tid < M_GT) gbS[tid] = ((const float4*)gt_boxes)[b * M_GT + tid];

    const float4 p  = ((const float4*)pred_boxes)[b * N_PRED + tid];
    const float  po = pred_obj[b * N_PRED + tid];
    pbS[tid] = p;
    __syncthreads();

    const float objc = 1.f - 1.f / (1.f + __expf(-po));
    float cr[M_GT];
    float bestv = INFINITY; int bestj = 0;
#pragma unroll
    for (int j = 0; j < M_GT; ++j) {
        float4 g = gbS[j];
        float l1 = fabsf(p.x - g.x) + fabsf(p.y - g.y) +
                   fabsf(p.z - g.z) + fabsf(p.w - g.w);
        float c = l1 + (1.f - giou_f(p, g)) + objc;
        cr[j] = c;
        if (c < bestv) { bestv = c; bestj = j; }  // strict < -> smallest j
    }

    unsigned colUsed = 0;
    bool rowUsed = false;
    int my_pi = 0, my_gj = 0;   // thread t (t<32) records match t

    for (int t = 0; t < M_GT; ++t) {
        const unsigned cand = rowUsed ? 0xFFFFFFFFu : __float_as_uint(bestv);
        const int      flat = tid * M_GT + bestj;
        // intra-wave DPP min-scan on value
        unsigned scan = cand;
        DPP_MIN(0x111, 0xF);   // row_shr:1
        DPP_MIN(0x112, 0xF);   // row_shr:2
        DPP_MIN(0x114, 0xF);   // row_shr:4
        DPP_MIN(0x118, 0xF);   // row_shr:8
        DPP_MIN(0x142, 0xA);   // row_bcast15 -> rows 1,3
        DPP_MIN(0x143, 0xC);   // row_bcast31 -> rows 2,3
        const unsigned vmin = (unsigned)__builtin_amdgcn_readlane((int)scan, 63);
        const unsigned long long mk = __ballot(cand == vmin);
        const int srcl  = __ffsll(mk) - 1;   // lowest lane = smallest row
        const int flatw = __builtin_amdgcn_readlane(flat, srcl);
        if (ln == 0)
            wkeyd[t & 1][wv] = ((unsigned long long)vmin << 32) | (unsigned)flatw;
        __syncthreads();
        const unsigned long long* wk = wkeyd[t & 1];
        unsigned long long g0 = wk[0] < wk[1] ? wk[0] : wk[1];
        unsigned long long g1 = wk[2] < wk[3] ? wk[2] : wk[3];
        unsigned long long g  = g0 < g1 ? g0 : g1;
        const int gflat = (int)(g & 0x1FFFu);
        const int wi = gflat >> 5;
        const int wj = gflat & 31;
        if (tid == t)  { my_pi = wi; my_gj = wj; }
        if (tid == wi) rowUsed = true;
        colUsed |= 1u << wj;
        if (!rowUsed && bestj == wj) {   // rescan own register row
            float bv = INFINITY; int bj = 0;
#pragma unroll
            for (int j = 0; j < M_GT; ++j) {
                float c = ((colUsed >> j) & 1) ? INFINITY : cr[j];
                if (c < bv) { bv = c; bj = j; }
            }
            bestv = bv; bestj = bj;
        }
        // no trailing barrier: next iteration writes the other wkeyd buffer
    }

    if (tid < M_GT) {
        pis[b * M_GT + tid] = my_pi;
        gjs[b * M_GT + tid] = my_gj;
    }

    // bbox loss over matched pairs (threads 0..31, wave 0)
    float l1sum = 0.f, gsum = 0.f;
    if (tid < M_GT) {
        float4 mp = pbS[my_pi];
        float4 mg = gbS[my_gj];
        l1sum = fabsf(mp.x - mg.x) + fabsf(mp.y - mg.y) +
                fabsf(mp.z - mg.z) + fabsf(mp.w - mg.w);
        gsum = 1.f - giou_f(mp, mg);
    }
    // objectness BCE: each thread contributes its own row
    float osum = fmaxf(po, 0.f) - po * (rowUsed ? 1.f : 0.f) +
                 log1pf(__expf(-fabsf(po)));
    for (int off = 32; off > 0; off >>= 1) {
        l1sum += __shfl_xor(l1sum, off);
        gsum  += __shfl_xor(gsum,  off);
        osum  += __shfl_xor(osum,  off);
    }
    if (ln == 0) wosum[wv] = osum;
    __syncthreads();
    if (tid == 0) {
        float l1_loss   = l1sum / 128.f;                       // mean over (32,4)
        float giou_loss = fminf(fmaxf(gsum / 32.f, 0.f), 2.f); // clip [0,2]
        bbox_out[b] = fmaxf(l1_loss + giou_loss, 0.f);
        float ot = wosum[0] + wosum[1] + wosum[2] + wosum[3];
        obj_out[b]  = fmaxf(ot / 256.f, 0.f);
    }
}

// ===== caption (byte-identical to R6) =====
__global__ __launch_bounds__(256) void caption_lse_kernel(
    const float* __restrict__ cl, const int* __restrict__ gt_tokens,
    const int* __restrict__ pis, const int* __restrict__ gjs,
    float* __restrict__ pm, float* __restrict__ ps, float* __restrict__ tl)
{
    const int bid = blockIdx.x;
    const int h   = bid & 1;
    const int r   = bid >> 1;
    const int b   = r / (M_GT * P_POS);
    const int rem = r % (M_GT * P_POS);
    const int k   = rem / P_POS;
    const int p   = rem % P_POS;
    const int tid = threadIdx.x;
    const int wv  = tid >> 6;
    const int ln  = tid & 63;

    const int n = pis[b * M_GT + k];
    const float* row = cl + ((size_t)(b * N_PRED + n) * L_TOK + p) * V_VOCAB;
    const float4* row4 = (const float4*)row;

    const int base = h * HALF4;
    const int end  = base + HALF4;
    float m0 = -INFINITY, s0 = 0.f;
    float m1 = -INFINITY, s1 = 0.f;
    for (int idx = base + tid; idx < end; idx += 512) {
        {
            float4 v = row4[idx];
            float m4 = fmaxf(fmaxf(v.x, v.y), fmaxf(v.z, v.w));
            float mn = fmaxf(m0, m4);
            s0 = s0 * __expf(m0 - mn) +
                 __expf(v.x - mn) + __expf(v.y - mn) +
                 __expf(v.z - mn) + __expf(v.w - mn);
            m0 = mn;
        }
        int i2 = idx + 256;
        if (i2 < end) {
            float4 v = row4[i2];
            float m4 = fmaxf(fmaxf(v.x, v.y), fmaxf(v.z, v.w));
            float mn = fmaxf(m1, m4);
            s1 = s1 * __expf(m1 - mn) +
                 __expf(v.x - mn) + __expf(v.y - mn) +
                 __expf(v.z - mn) + __expf(v.w - mn);
            m1 = mn;
        }
    }
    float m = fmaxf(m0, m1);
    float s = s0 * __expf(m0 - m) + s1 * __expf(m1 - m);

    for (int off = 32; off > 0; off >>= 1) {
        float mo = __shfl_xor(m, off);
        float so = __shfl_xor(s, off);
        float mm = fmaxf(m, mo);
        s = s * __expf(m - mm) + so * __expf(mo - mm);
        m = mm;
    }

    __shared__ float wm[4], wsum[4];
    if (ln == 0) { wm[wv] = m; wsum[wv] = s; }
    __syncthreads();
    if (tid == 0) {
        float mm = fmaxf(fmaxf(wm[0], wm[1]), fmaxf(wm[2], wm[3]));
        float st = wsum[0] * __expf(wm[0] - mm) + wsum[1] * __expf(wm[1] - mm) +
                   wsum[2] * __expf(wm[2] - mm) + wsum[3] * __expf(wm[3] - mm);
        pm[bid] = mm;
        ps[bid] = st;
        if (h == 0) {
            const int gj  = gjs[b * M_GT + k];
            const int tgt = gt_tokens[(b * M_GT + gj) * L_TOK + (p + 1)];
            tl[r] = row[tgt];
        }
    }
}

// ===== finalize (byte-identical to R6) =====
__global__ __launch_bounds__(64) void finalize_kernel(
    const float* __restrict__ pm, const float* __restrict__ ps,
    const float* __restrict__ tl,
    const float* __restrict__ bbox, const float* __restrict__ obj,
    float* __restrict__ out)
{
    const int l = threadIdx.x;      // l = b*32 + k
    float sum = 0.f;
#pragma unroll
    for (int p = 0; p < P_POS; ++p) {
        int r = l * P_POS + p;
        float m0 = pm[2*r],   s0 = ps[2*r];
        float m1 = pm[2*r+1], s1 = ps[2*r+1];
        float mm = fmaxf(m0, m1);
        float s  = s0 * __expf(m0 - mm) + s1 * __expf(m1 - mm);
        sum += mm + __logf(s) - tl[r];
    }
    float cek = fmaxf(sum / (float)P_POS, 0.f);   // clip(ce,0) per match
    for (int off = 16; off > 0; off >>= 1) cek += __shfl_xor(cek, off);
    float cap_b = fmaxf(cek / (float)M_GT, 0.f);  // clip(mean,0) per sample
    float cap0 = __shfl(cap_b, 0);
    float cap1 = __shfl(cap_b, 32);
    if (l == 0) {
        float bb0 = bbox[0], bb1 = bbox[1];
        float ob0 = obj[0],  ob1 = obj[1];
        float per0 = 5.f * bb0 + 0.1f * cap0 + ob0;
        float per1 = 5.f * bb1 + 0.1f * cap1 + ob1;
        out[0] = fmaxf(0.5f * (per0 + per1), 0.f);
        out[1] = 5.f  * 0.5f * (bb0 + bb1);
        out[2] = 0.1f * 0.5f * (cap0 + cap1);
        out[3] = 0.5f * (ob0 + ob1);
    }
}

extern "C" void kernel_launch(void* const* d_in, const int* in_sizes, int n_in,
                              void* d_out, int out_size, void* d_ws, size_t ws_size,
                              hipStream_t stream) {
    const float* pred_boxes = (const float*)d_in[0];   // (2,256,4)
    const float* pred_obj   = (const float*)d_in[1];   // (2,256)
    const float* cap_logits = (const float*)d_in[2];   // (2,256,16,32000)
    const float* gt_boxes   = (const float*)d_in[3];   // (2,32,4)
    const int*   gt_tokens  = (const int*)d_in[4];     // (2,32,16) int32
    float* out = (float*)d_out;                        // (4,)

    int*   pis  = (int*)d_ws;                  // 64 ints
    int*   gjs  = pis + B_SZ * M_GT;           // 64 ints
    float* bbox = (float*)(gjs + B_SZ * M_GT); // 2 floats
    float* obj  = bbox + B_SZ;                 // 2 floats
    float* pm   = obj + B_SZ;                  // 1920 floats (960 rows x 2)
    float* ps   = pm + 2 * NROW;               // 1920 floats
    float* tl   = ps + 2 * NROW;               // 960 floats

    match_bbox_obj_kernel<<<B_SZ, 256, 0, stream>>>(
        pred_boxes, pred_obj, gt_boxes, pis, gjs, bbox, obj);
    caption_lse_kernel<<<2 * NROW, 256, 0, stream>>>(
        cap_logits, gt_tokens, pis, gjs, pm, ps, tl);
    finalize_kernel<<<1, 64, 0, stream>>>(pm, ps, tl, bbox, obj, out);
}

// Round 9
// 76.600 us; speedup vs baseline: 1.8766x; 1.0124x over previous
//
#include <hip/hip_runtime.h>
#include <math.h>

#define B_SZ 2
#define N_PRED 256
#define M_GT 32
#define L_TOK 16
#define V_VOCAB 32000
#define P_POS 15            // L_TOK-1 predicted positions
#define NROW 960            // B*M*P = 2*32*15 caption rows
#define HALF4 4000          // float4s per half-row (32000/4/2)

__device__ __forceinline__ float giou_f(float4 b1, float4 b2) {
    float ax1 = fminf(b1.x, b1.z), ay1 = fminf(b1.y, b1.w);
    float ax2 = fmaxf(b1.x, b1.z), ay2 = fmaxf(b1.y, b1.w);
    float bx1 = fminf(b2.x, b2.z), by1 = fminf(b2.y, b2.w);
    float bx2 = fmaxf(b2.x, b2.z), by2 = fmaxf(b2.y, b2.w);
    float xi1 = fmaxf(ax1, bx1), yi1 = fmaxf(ay1, by1);
    float xi2 = fminf(ax2, bx2), yi2 = fminf(ay2, by2);
    float inter = fmaxf(xi2 - xi1, 0.f) * fmaxf(yi2 - yi1, 0.f);
    float a1 = (ax2 - ax1) * (ay2 - ay1);
    float a2 = (bx2 - bx1) * (by2 - by1);
    float uni = a1 + a2 - inter;
    float iou = inter / (uni + 1e-7f);
    float xe1 = fminf(ax1, bx1), ye1 = fminf(ay1, by1);
    float xe2 = fmaxf(ax2, bx2), ye2 = fmaxf(ay2, by2);
    float enc = (xe2 - xe1) * (ye2 - ye1);
    return iou - (enc - uni) / (enc + 1e-7f);
}

// 6-step DPP inclusive min-scan step on 32-bit unsigned `scan`; lanes with
// no source get old=0xFFFFFFFF (never wins). Verified on HW in R5/R7/R8.
#define DPP_MIN(ctrl, rmask)                                               \
    {                                                                      \
        unsigned nv = (unsigned)__builtin_amdgcn_update_dpp(               \
            (int)0xFFFFFFFF, (int)scan, (ctrl), (rmask), 0xF, false);      \
        if (nv < scan) scan = nv;                                          \
    }

// ===== match (byte-identical to R8) =====
__global__ __launch_bounds__(256) void match_bbox_obj_kernel(
    const float* __restrict__ pred_boxes, const float* __restrict__ pred_obj,
    const float* __restrict__ gt_boxes,
    int* __restrict__ pis, int* __restrict__ gjs,
    float* __restrict__ bbox_out, float* __restrict__ obj_out)
{
    const int b   = blockIdx.x;
    const int tid = threadIdx.x;          // = pred row index
    const int wv  = tid >> 6;
    const int ln  = tid & 63;

    __shared__ float4 gbS[M_GT];
    __shared__ float4 pbS[N_PRED];
    __shared__ unsigned long long wkeyd[2][4];
    __shared__ float wosum[4];

    if (tid < M_GT) gbS[tid] = ((const float4*)gt_boxes)[b * M_GT + tid];

    const float4 p  = ((const float4*)pred_boxes)[b * N_PRED + tid];
    const float  po = pred_obj[b * N_PRED + tid];
    pbS[tid] = p;
    __syncthreads();

    const float objc = 1.f - 1.f / (1.f + __expf(-po));
    float cr[M_GT];
    float bestv = INFINITY; int bestj = 0;
#pragma unroll
    for (int j = 0; j < M_GT; ++j) {
        float4 g = gbS[j];
        float l1 = fabsf(p.x - g.x) + fabsf(p.y - g.y) +
                   fabsf(p.z - g.z) + fabsf(p.w - g.w);
        float c = l1 + (1.f - giou_f(p, g)) + objc;
        cr[j] = c;
        if (c < bestv) { bestv = c; bestj = j; }  // strict < -> smallest j
    }

    unsigned colUsed = 0;
    bool rowUsed = false;
    int my_pi = 0, my_gj = 0;   // thread t (t<32) records match t

    for (int t = 0; t < M_GT; ++t) {
        const unsigned cand = rowUsed ? 0xFFFFFFFFu : __float_as_uint(bestv);
        const int      flat = tid * M_GT + bestj;
        unsigned scan = cand;
        DPP_MIN(0x111, 0xF);   // row_shr:1
        DPP_MIN(0x112, 0xF);   // row_shr:2
        DPP_MIN(0x114, 0xF);   // row_shr:4
        DPP_MIN(0x118, 0xF);   // row_shr:8
        DPP_MIN(0x142, 0xA);   // row_bcast15 -> rows 1,3
        DPP_MIN(0x143, 0xC);   // row_bcast31 -> rows 2,3
        const unsigned vmin = (unsigned)__builtin_amdgcn_readlane((int)scan, 63);
        const unsigned long long mk = __ballot(cand == vmin);
        const int srcl  = __ffsll(mk) - 1;   // lowest lane = smallest row
        const int flatw = __builtin_amdgcn_readlane(flat, srcl);
        if (ln == 0)
            wkeyd[t & 1][wv] = ((unsigned long long)vmin << 32) | (unsigned)flatw;
        __syncthreads();
        const unsigned long long* wk = wkeyd[t & 1];
        unsigned long long g0 = wk[0] < wk[1] ? wk[0] : wk[1];
        unsigned long long g1 = wk[2] < wk[3] ? wk[2] : wk[3];
        unsigned long long g  = g0 < g1 ? g0 : g1;
        const int gflat = (int)(g & 0x1FFFu);
        const int wi = gflat >> 5;
        const int wj = gflat & 31;
        if (tid == t)  { my_pi = wi; my_gj = wj; }
        if (tid == wi) rowUsed = true;
        colUsed |= 1u << wj;
        if (!rowUsed && bestj == wj) {   // rescan own register row
            float bv = INFINITY; int bj = 0;
#pragma unroll
            for (int j = 0; j < M_GT; ++j) {
                float c = ((colUsed >> j) & 1) ? INFINITY : cr[j];
                if (c < bv) { bv = c; bj = j; }
            }
            bestv = bv; bestj = bj;
        }
        // no trailing barrier: next iteration writes the other wkeyd buffer
    }

    if (tid < M_GT) {
        pis[b * M_GT + tid] = my_pi;
        gjs[b * M_GT + tid] = my_gj;
    }

    float l1sum = 0.f, gsum = 0.f;
    if (tid < M_GT) {
        float4 mp = pbS[my_pi];
        float4 mg = gbS[my_gj];
        l1sum = fabsf(mp.x - mg.x) + fabsf(mp.y - mg.y) +
                fabsf(mp.z - mg.z) + fabsf(mp.w - mg.w);
        gsum = 1.f - giou_f(mp, mg);
    }
    float osum = fmaxf(po, 0.f) - po * (rowUsed ? 1.f : 0.f) +
                 log1pf(__expf(-fabsf(po)));
    for (int off = 32; off > 0; off >>= 1) {
        l1sum += __shfl_xor(l1sum, off);
        gsum  += __shfl_xor(gsum,  off);
        osum  += __shfl_xor(osum,  off);
    }
    if (ln == 0) wosum[wv] = osum;
    __syncthreads();
    if (tid == 0) {
        float l1_loss   = l1sum / 128.f;                       // mean over (32,4)
        float giou_loss = fminf(fmaxf(gsum / 32.f, 0.f), 2.f); // clip [0,2]
        bbox_out[b] = fmaxf(l1_loss + giou_loss, 0.f);
        float ot = wosum[0] + wosum[1] + wosum[2] + wosum[3];
        obj_out[b]  = fmaxf(ot / 256.f, 0.f);
    }
}

// ===== caption: deep-MLP (memory-level-parallelism) version =====
// One block per (row r, half h). 16 slots of 256 float4; loads issued in
// batches of 8 independent global_load_dwordx4 per thread (128 B in flight
// per lane) feeding 4 independent (m,s) chains. Slot 15 guarded with a
// neutral -INF vector (exp(-inf - m) = 0; chain 3's first fold is slot 3,
// unguarded, so m is finite before any -INF enters).
__device__ __forceinline__ void fold4(float4 v, float& m, float& s) {
    float m4 = fmaxf(fmaxf(v.x, v.y), fmaxf(v.z, v.w));
    float mn = fmaxf(m, m4);
    s = s * __expf(m - mn) +
        __expf(v.x - mn) + __expf(v.y - mn) +
        __expf(v.z - mn) + __expf(v.w - mn);
    m = mn;
}

__global__ __launch_bounds__(256) void caption_lse_kernel(
    const float* __restrict__ cl, const int* __restrict__ gt_tokens,
    const int* __restrict__ pis, const int* __restrict__ gjs,
    float* __restrict__ pm, float* __restrict__ ps, float* __restrict__ tl)
{
    const int bid = blockIdx.x;
    const int h   = bid & 1;
    const int r   = bid >> 1;
    const int b   = r / (M_GT * P_POS);
    const int rem = r % (M_GT * P_POS);
    const int k   = rem / P_POS;
    const int p   = rem % P_POS;
    const int tid = threadIdx.x;
    const int wv  = tid >> 6;
    const int ln  = tid & 63;

    const int n = pis[b * M_GT + k];
    const float* row = cl + ((size_t)(b * N_PRED + n) * L_TOK + p) * V_VOCAB;
    const float4* row4 = (const float4*)row;
    const int base = h * HALF4;

    float mc[4] = {-INFINITY, -INFINITY, -INFINITY, -INFINITY};
    float sc[4] = {0.f, 0.f, 0.f, 0.f};
    float4 v[8];

    // batch 0: slots 0..7 (all in-range: 255 + 7*256 = 2047 < 4000)
#pragma unroll
    for (int e = 0; e < 8; ++e) v[e] = row4[base + tid + e * 256];
#pragma unroll
    for (int e = 0; e < 8; ++e) fold4(v[e], mc[e & 3], sc[e & 3]);

    // batch 1: slots 8..15; slot 15 valid iff tid < 4000 - 15*256 = 160
    const bool full = tid < (HALF4 - 15 * 256);
#pragma unroll
    for (int e = 8; e < 16; ++e) {
        if (e < 15 || full) v[e - 8] = row4[base + tid + e * 256];
        else v[e - 8] = make_float4(-INFINITY, -INFINITY, -INFINITY, -INFINITY);
    }
#pragma unroll
    for (int e = 8; e < 16; ++e) fold4(v[e - 8], mc[e & 3], sc[e & 3]);

    // merge the 4 chains
    float m = fmaxf(fmaxf(mc[0], mc[1]), fmaxf(mc[2], mc[3]));
    float s = sc[0] * __expf(mc[0] - m) + sc[1] * __expf(mc[1] - m) +
              sc[2] * __expf(mc[2] - m) + sc[3] * __expf(mc[3] - m);

    // intra-wave (m,s) merge — no barriers
    for (int off = 32; off > 0; off >>= 1) {
        float mo = __shfl_xor(m, off);
        float so = __shfl_xor(s, off);
        float mm = fmaxf(m, mo);
        s = s * __expf(m - mm) + so * __expf(mo - mm);
        m = mm;
    }

    __shared__ float wm[4], wsum[4];
    if (ln == 0) { wm[wv] = m; wsum[wv] = s; }
    __syncthreads();
    if (tid == 0) {
        float mm = fmaxf(fmaxf(wm[0], wm[1]), fmaxf(wm[2], wm[3]));
        float st = wsum[0] * __expf(wm[0] - mm) + wsum[1] * __expf(wm[1] - mm) +
                   wsum[2] * __expf(wm[2] - mm) + wsum[3] * __expf(wm[3] - mm);
        pm[bid] = mm;
        ps[bid] = st;
        if (h == 0) {
            const int gj  = gjs[b * M_GT + k];
            const int tgt = gt_tokens[(b * M_GT + gj) * L_TOK + (p + 1)];
            tl[r] = row[tgt];
        }
    }
}

// ===== finalize (byte-identical to R8) =====
__global__ __launch_bounds__(64) void finalize_kernel(
    const float* __restrict__ pm, const float* __restrict__ ps,
    const float* __restrict__ tl,
    const float* __restrict__ bbox, const float* __restrict__ obj,
    float* __restrict__ out)
{
    const int l = threadIdx.x;      // l = b*32 + k
    float sum = 0.f;
#pragma unroll
    for (int p = 0; p < P_POS; ++p) {
        int r = l * P_POS + p;
        float m0 = pm[2*r],   s0 = ps[2*r];
        float m1 = pm[2*r+1], s1 = ps[2*r+1];
        float mm = fmaxf(m0, m1);
        float s  = s0 * __expf(m0 - mm) + s1 * __expf(m1 - mm);
        sum += mm + __logf(s) - tl[r];
    }
    float cek = fmaxf(sum / (float)P_POS, 0.f);   // clip(ce,0) per match
    for (int off = 16; off > 0; off >>= 1) cek += __shfl_xor(cek, off);
    float cap_b = fmaxf(cek / (float)M_GT, 0.f);  // clip(mean,0) per sample
    float cap0 = __shfl(cap_b, 0);
    float cap1 = __shfl(cap_b, 32);
    if (l == 0) {
        float bb0 = bbox[0], bb1 = bbox[1];
        float ob0 = obj[0],  ob1 = obj[1];
        float per0 = 5.f * bb0 + 0.1f * cap0 + ob0;
        float per1 = 5.f * bb1 + 0.1f * cap1 + ob1;
        out[0] = fmaxf(0.5f * (per0 + per1), 0.f);
        out[1] = 5.f  * 0.5f * (bb0 + bb1);
        out[2] = 0.1f * 0.5f * (cap0 + cap1);
        out[3] = 0.5f * (ob0 + ob1);
    }
}

extern "C" void kernel_launch(void* const* d_in, const int* in_sizes, int n_in,
                              void* d_out, int out_size, void* d_ws, size_t ws_size,
                              hipStream_t stream) {
    const float* pred_boxes = (const float*)d_in[0];   // (2,256,4)
    const float* pred_obj   = (const float*)d_in[1];   // (2,256)
    const float* cap_logits = (const float*)d_in[2];   // (2,256,16,32000)
    const float* gt_boxes   = (const float*)d_in[3];   // (2,32,4)
    const int*   gt_tokens  = (const int*)d_in[4];     // (2,32,16) int32
    float* out = (float*)d_out;                        // (4,)

    int*   pis  = (int*)d_ws;                  // 64 ints
    int*   gjs  = pis + B_SZ * M_GT;           // 64 ints
    float* bbox = (float*)(gjs + B_SZ * M_GT); // 2 floats
    float* obj  = bbox + B_SZ;                 // 2 floats
    float* pm   = obj + B_SZ;                  // 1920 floats (960 rows x 2)
    float* ps   = pm + 2 * NROW;               // 1920 floats
    float* tl   = ps + 2 * NROW;               // 960 floats

    match_bbox_obj_kernel<<<B_SZ, 256, 0, stream>>>(
        pred_boxes, pred_obj, gt_boxes, pis, gjs, bbox, obj);
    caption_lse_kernel<<<2 * NROW, 256, 0, stream>>>(
        cap_logits, gt_tokens, pis, gjs, pm, ps, tl);
    finalize_kernel<<<1, 64, 0, stream>>>(pm, ps, tl, bbox, obj, out);
}